// Round 3
// baseline (415.125 us; speedup 1.0000x reference)
//
#include <hip/hip_runtime.h>
#include <hip/hip_bf16.h>
#include <stdint.h>

#define NSEQ 4096
#define DDIM 768
#define NB   4
#define NTRI 528          // 32*33/2 lower-tri 128-blocks per batch
#define BLKE 16384        // 128*128

typedef short short8 __attribute__((ext_vector_type(8)));
typedef float f32x16 __attribute__((ext_vector_type(16)));

__device__ __forceinline__ unsigned short f2bf(float f) {
    unsigned int u = __float_as_uint(f);
    u += 0x7fffu + ((u >> 16) & 1u);
    return (unsigned short)(u >> 16);
}
__device__ __forceinline__ short8 cvt8(const float* __restrict__ p) {
    float4 x = *(const float4*)p;
    float4 y = *(const float4*)(p + 4);
    union { short8 s; __hip_bfloat162 h[4]; } u;
    u.h[0] = __float22bfloat162_rn(make_float2(x.x, x.y));
    u.h[1] = __float22bfloat162_rn(make_float2(x.z, x.w));
    u.h[2] = __float22bfloat162_rn(make_float2(y.x, y.y));
    u.h[3] = __float22bfloat162_rn(make_float2(y.z, y.w));
    return u.s;
}

// async global->LDS, 16B per lane (global_load_lds_dwordx4)
typedef const __attribute__((address_space(1))) unsigned int ga_u32;
typedef __attribute__((address_space(3))) unsigned int ls_u32;
__device__ __forceinline__ void gload_lds16(const void* g, void* l) {
    __builtin_amdgcn_global_load_lds((ga_u32*)(uintptr_t)g, (ls_u32*)(uintptr_t)l, 16, 0, 0);
}

// ---------------------------------------------------------------------------
// 256-thread XOR-swizzled staging + compute (gemm_pv only; verified baseline).
// ---------------------------------------------------------------------------
__device__ __forceinline__ void stage_tile(const unsigned short* gbase, int stride,
                                           unsigned short* lds, int tid) {
    const int lane = tid & 63, wv = tid >> 6;
    const int r8  = lane >> 3;
    const int cl  = (lane & 7) * 8;          // LDS dest col group (lane*16B)
#pragma unroll
    for (int t = 0; t < 4; ++t) {
        const int row = wv * 32 + t * 8 + r8;
        const int csw = (((lane & 7) ^ r8 ^ t) & 7) * 8;   // swizzled global col
        gload_lds16(gbase + (size_t)row * stride + csw, lds + row * 64 + cl);
    }
}

__device__ __forceinline__ void mma_tiles(const unsigned short* As, const unsigned short* Bs,
                                          f32x16 acc[2][2], int wm, int wn, int lane) {
    const int r32 = lane & 31;
    const int hi  = lane >> 5;
    const int sw  = (lane & 7) ^ ((lane >> 3) & 3);
#pragma unroll
    for (int c = 0; c < 4; ++c) {
        const int chunk = (((c * 2 + hi) ^ sw) & 7) * 8;
        short8 af[2], bg[2];
#pragma unroll
        for (int mt = 0; mt < 2; ++mt)
            af[mt] = *(const short8*)(As + (wm * 64 + mt * 32 + r32) * 64 + chunk);
#pragma unroll
        for (int nt = 0; nt < 2; ++nt)
            bg[nt] = *(const short8*)(Bs + (wn * 64 + nt * 32 + r32) * 64 + chunk);
#pragma unroll
        for (int mt = 0; mt < 2; ++mt)
#pragma unroll
            for (int nt = 0; nt < 2; ++nt)
                acc[mt][nt] = __builtin_amdgcn_mfma_f32_32x32x16_bf16(af[mt], bg[nt], acc[mt][nt], 0, 0, 0);
    }
}

// C/D layout (m74/m101-verified): col = lane&31, row = (reg&3)+8*(reg>>2)+4*(lane>>5)
__device__ __forceinline__ int crow(int reg, int hi) {
    return (reg & 3) + 8 * (reg >> 2) + 4 * hi;
}

// ---------------------------------------------------------------------------
// 512-thread counted-vmcnt pipelined 256x256x768 GEMM core (T4 proper).
//
// LDS per array: 2 bufs x 4 K16-slices, slice = [256 rows][2 chunks of 16B]
// (8 KB, natural layout). Every ds_read_b128 (64 lanes = rows R..R+31 x
// hi 0/1) and every global_load_lds shot is a permutation of a contiguous
// 1 KB block -> bank-balanced, no swizzle needed.
//
// Stage event e (2 loads/thread: A-slice + B-slice) targets slot
// (buf=(e>>2)&1, slice=e&3), consumed at phase e, issued at phase e-7.
// Slot last read at phase e-8 -> one barrier separates last read (fenced by
// reader's lgkmcnt(0)-before-MFMA) from overwrite. Per phase:
//   vmcnt(12) [6 newer events x 2 loads stay in flight -> MLP never drains]
//   -> s_barrier (collects all waves' waits -> slice globally visible)
//   -> sched_barrier(0) [no hoist of stage/reads above barrier]
//   -> issue event g+7 -> 6 ds_read_b128 -> lgkmcnt(0)+sched_barrier(0)
//   -> setprio(1) 8 MFMA setprio(0).
// Tail events (e>=48) clamp SOURCE to tile 11 and write only dead slots.
// ---------------------------------------------------------------------------
__device__ __forceinline__ void stage_slice(const unsigned short* __restrict__ A,
                                            const unsigned short* __restrict__ B,
                                            unsigned short* AsB, unsigned short* BsB,
                                            int tid, int e) {
    const int t4 = e >> 2;
    const int te = (t4 < 12) ? t4 : 11;      // clamp source for dummy tail events
    const int ce = e & 3;
    const int buf = t4 & 1;
    const int so = (buf * 4 + ce) * 4096 + tid * 8;          // ushort units
    const size_t goff = (size_t)(tid >> 1) * DDIM + te * 64 + ce * 16 + (tid & 1) * 8;
    gload_lds16(A + goff, AsB + so);
    gload_lds16(B + goff, BsB + so);
}

__device__ __forceinline__ void gemm256_core(const unsigned short* __restrict__ A,
                                             const unsigned short* __restrict__ B,
                                             unsigned short* AsB, unsigned short* BsB,
                                             f32x16 (&acc)[4][2], int tid) {
    const int lane = tid & 63, r32 = lane & 31, hi = lane >> 5;
    const int wv = tid >> 6, wm = wv >> 2, wn = wv & 3;
#pragma unroll
    for (int e = 0; e < 7; ++e) stage_slice(A, B, AsB, BsB, tid, e);

    for (int t = 0; t < 12; ++t) {
        const int buf = t & 1;
#pragma unroll
        for (int c = 0; c < 4; ++c) {
            asm volatile("s_waitcnt vmcnt(12)" ::: "memory");
            __builtin_amdgcn_s_barrier();
            __builtin_amdgcn_sched_barrier(0);
            stage_slice(A, B, AsB, BsB, tid, 4 * t + c + 7);
            const unsigned short* Asl = AsB + (buf * 4 + c) * 4096;
            const unsigned short* Bsl = BsB + (buf * 4 + c) * 4096;
            short8 af[4], bg[2];
#pragma unroll
            for (int mt = 0; mt < 4; ++mt)
                af[mt] = *(const short8*)(Asl + (wm * 128 + mt * 32 + r32) * 16 + hi * 8);
#pragma unroll
            for (int nt = 0; nt < 2; ++nt)
                bg[nt] = *(const short8*)(Bsl + (wn * 64 + nt * 32 + r32) * 16 + hi * 8);
            asm volatile("s_waitcnt lgkmcnt(0)" ::: "memory");
            __builtin_amdgcn_sched_barrier(0);
            __builtin_amdgcn_s_setprio(1);
#pragma unroll
            for (int mt = 0; mt < 4; ++mt) {
                acc[mt][0] = __builtin_amdgcn_mfma_f32_32x32x16_bf16(af[mt], bg[0], acc[mt][0], 0, 0, 0);
                acc[mt][1] = __builtin_amdgcn_mfma_f32_32x32x16_bf16(af[mt], bg[1], acc[mt][1], 0, 0, 0);
            }
            __builtin_amdgcn_s_setprio(0);
        }
    }
}

// ---------------------------------------------------------------------------
// fp32 -> bf16 convert: X (6144 blocks), Wq/Wk/Wv (288 blocks each).
// Extra 16 blocks zero the row-sum accumulator L; block 0 zeroes the counter.
// ---------------------------------------------------------------------------
__global__ __launch_bounds__(256)
void convert_kernel(const float* __restrict__ X, const float* __restrict__ Wq,
                    const float* __restrict__ Wk, const float* __restrict__ Wv,
                    unsigned short* __restrict__ Xb, unsigned short* __restrict__ Wb,
                    float* __restrict__ L, unsigned int* __restrict__ counter)
{
    const int bid = blockIdx.x;
    if (bid == 0 && threadIdx.x == 0) *counter = 0u;
    if (bid >= 7008) {                      // zero L: 16 blocks x 1024 floats
        const int idx = (bid - 7008) * 1024 + threadIdx.x * 4;
        *(float4*)(L + idx) = make_float4(0.f, 0.f, 0.f, 0.f);
        return;
    }
    const float* src; unsigned short* dst; size_t off;
    if (bid < 6144) { src = X; dst = Xb; off = (size_t)bid * 2048; }
    else {
        const int wbid = bid - 6144;
        const int wi = wbid / 288;
        src = (wi == 0) ? Wq : ((wi == 1) ? Wk : Wv);
        dst = Wb + (size_t)wi * (DDIM * DDIM);
        off = (size_t)(wbid - wi * 288) * 2048;
    }
    const size_t i = off + (size_t)threadIdx.x * 8;
    *(short8*)(dst + i) = cvt8(src + i);
}

// ---------------------------------------------------------------------------
// QKV: C = Xb * Wb^T per weight. 256x256 tile, BK=64, 512 thr, 8-wave 2Mx4N,
// counted-vmcnt pipeline. grid (64,3,3).
// ---------------------------------------------------------------------------
__global__ __launch_bounds__(512, 2)
void qkv_gemm(const unsigned short* __restrict__ Xb, const unsigned short* __restrict__ Wb,
              unsigned short* __restrict__ Qb, unsigned short* __restrict__ Kb,
              unsigned short* __restrict__ Vtb)
{
    const int tid = threadIdx.x, lane = tid & 63, wv = tid >> 6;
    const int r32 = lane & 31, hi = lane >> 5, wm = wv >> 2, wn = wv & 3;
    const int m0 = blockIdx.x * 256, n0 = blockIdx.y * 256, widx = blockIdx.z;
    const unsigned short* A = Xb + (size_t)m0 * DDIM;
    const unsigned short* B = Wb + (size_t)widx * (DDIM * DDIM) + (size_t)n0 * DDIM;

    __shared__ __align__(16) unsigned short As[2 * 4 * 4096];
    __shared__ __align__(16) unsigned short Bs[2 * 4 * 4096];

    f32x16 acc[4][2] = {};
    gemm256_core(A, B, As, Bs, acc, tid);

    const int m_base = m0 + wm * 128, o_base = n0 + wn * 64;
    if (widx < 2) {
        unsigned short* dst = (widx == 0) ? Qb : Kb;
#pragma unroll
        for (int mt = 0; mt < 4; ++mt)
#pragma unroll
            for (int nt = 0; nt < 2; ++nt)
#pragma unroll
                for (int reg = 0; reg < 16; ++reg)
                    dst[(size_t)(m_base + mt * 32 + crow(reg, hi)) * DDIM +
                        (o_base + nt * 32 + r32)] = f2bf(acc[mt][nt][reg]);
    } else {
        // Vt[b][o][n]: regs b4*4+0..3 are rows n..n+3 -> ushort4 pack
        const int bb = m0 >> 12;
        const int n_seq0 = (m0 & (NSEQ - 1)) + wm * 128;
#pragma unroll
        for (int mt = 0; mt < 4; ++mt)
#pragma unroll
            for (int nt = 0; nt < 2; ++nt) {
                const int o = o_base + nt * 32 + r32;
#pragma unroll
                for (int b4 = 0; b4 < 4; ++b4) {
                    ushort4 pk;
                    pk.x = f2bf(acc[mt][nt][b4 * 4 + 0]);
                    pk.y = f2bf(acc[mt][nt][b4 * 4 + 1]);
                    pk.z = f2bf(acc[mt][nt][b4 * 4 + 2]);
                    pk.w = f2bf(acc[mt][nt][b4 * 4 + 3]);
                    const int n = n_seq0 + mt * 32 + b4 * 8 + hi * 4;
                    *(ushort4*)(Vtb + ((size_t)(bb * DDIM + o)) * NSEQ + n) = pk;
                }
            }
    }
}

// ---------------------------------------------------------------------------
// S-pass at 256x256, softmax fused in epilogue. Sbuf keeps the verified
// 128-block tri layout: each wave's 128 rows/cols lie in exactly one
// 128-block (qb128 = 2*qsb+wm, kb128 = 2*ksb+(wn>>1)); waves with
// kb128>qb128 (upper half of diagonal superblock) store nothing.
// grid (136, 4), 512 thr.
// ---------------------------------------------------------------------------
__global__ __launch_bounds__(512, 2)
void gemm_s(const unsigned short* __restrict__ Qb, const unsigned short* __restrict__ Kb,
            unsigned short* __restrict__ Sbuf, float* __restrict__ L)
{
    const float c2 = 0.05205877475f;  // log2(e)/sqrt(768)
    const int tid = threadIdx.x, lane = tid & 63, wv = tid >> 6;
    const int r32 = lane & 31, hi = lane >> 5, wm = wv >> 2, wn = wv & 3;
    const int idx = blockIdx.x, bb = blockIdx.y;
    int qsb = (int)((sqrtf(8.f * idx + 1.f) - 1.f) * 0.5f);
    while ((qsb + 1) * (qsb + 2) / 2 <= idx) ++qsb;
    while (qsb * (qsb + 1) / 2 > idx) --qsb;
    const int ksb = idx - qsb * (qsb + 1) / 2;

    const unsigned short* A = Qb + ((size_t)bb * NSEQ + qsb * 256) * DDIM;
    const unsigned short* B = Kb + ((size_t)bb * NSEQ + ksb * 256) * DDIM;

    __shared__ __align__(16) unsigned short As[2 * 4 * 4096];
    __shared__ __align__(16) unsigned short Bs[2 * 4 * 4096];

    f32x16 acc[4][2] = {};
    gemm256_core(A, B, As, Bs, acc, tid);

    const int qb128 = qsb * 2 + wm;
    const int kb128 = ksb * 2 + (wn >> 1);
    if (kb128 > qb128) return;              // upper half of diag superblock: no slot
    unsigned short* Sblk = Sbuf + ((size_t)(bb * NTRI + qb128 * (qb128 + 1) / 2 + kb128)) * BLKE;
    float* Lrow = L + (size_t)bb * NSEQ + (qb128 << 7);
    const int coff = (wn & 1) * 64;
    const bool diag = (qb128 == kb128);
#pragma unroll
    for (int mt = 0; mt < 4; ++mt)
#pragma unroll
        for (int rp = 0; rp < 8; ++rp) {            // reg pair: rows row0, row0+1
            const int reg0 = rp * 2, reg1 = reg0 + 1;
            const int row0 = mt * 32 + crow(reg0, hi);   // 128-local
            const int row1 = row0 + 1;
            float vs0 = 0.f, vs1 = 0.f;
#pragma unroll
            for (int nt = 0; nt < 2; ++nt) {
                const int col = coff + nt * 32 + r32;    // 128-local
                float e0 = (diag && col > row0) ? 0.f : exp2f(acc[mt][nt][reg0] * c2);
                float e1 = (diag && col > row1) ? 0.f : exp2f(acc[mt][nt][reg1] * c2);
                union { __hip_bfloat162 h; ushort2 u; } cv;
                cv.h = __float22bfloat162_rn(make_float2(e0, e1));
                Sblk[row0 * 128 + col] = cv.u.x;
                Sblk[row1 * 128 + col] = cv.u.y;
                vs0 += e0;
                vs1 += e1;
            }
#pragma unroll
            for (int s = 1; s < 32; s <<= 1) {
                vs0 += __shfl_xor(vs0, s);
                vs1 += __shfl_xor(vs1, s);
            }
            if (r32 == 0) {
                atomicAdd(&Lrow[row0], vs0);
                atomicAdd(&Lrow[row1], vs1);
            }
        }
}

// ---------------------------------------------------------------------------
// O = P' V * (1/L[q]). Persistent queue, items (qb desc, b, ob). grid 512.
// (unchanged from verified baseline)
// ---------------------------------------------------------------------------
__global__ __launch_bounds__(256)
void gemm_pv(const unsigned short* __restrict__ P, const unsigned short* __restrict__ Vt,
             const float* __restrict__ L, float* __restrict__ Out,
             unsigned int* __restrict__ counter)
{
    const int tid = threadIdx.x, lane = tid & 63, wv = tid >> 6;
    const int r32 = lane & 31, hi = lane >> 5, wm = wv >> 1, wn = wv & 1;

    __shared__ __align__(16) unsigned short As[128 * 64];
    __shared__ __align__(16) unsigned short Bs[128 * 64];
    __shared__ float Linv[128];
    __shared__ unsigned int item_s;

    for (;;) {
        if (tid == 0) item_s = atomicAdd(counter, 1u);
        __syncthreads();
        const unsigned int item = item_s;
        if (item >= 768u) return;

        const int t = (int)(item / 24u);
        const int qb = 31 - t;
        const int rem = (int)(item - (unsigned)t * 24u);
        const int bb = rem / 6, ob = rem % 6;
        const size_t triq = (size_t)qb * (qb + 1) / 2;
        const unsigned short* Pbat = P + (size_t)bb * NTRI * BLKE;
        const unsigned short* Bbase = Vt + ((size_t)(bb * DDIM + ob * 128)) * NSEQ;
        const int niter = (qb + 1) * 2;

        if (tid < 128) Linv[tid] = 1.0f / L[(size_t)bb * NSEQ + qb * 128 + tid];

        f32x16 acc[2][2] = {};

        for (int it = 0; it < niter; ++it) {
            const int k0 = it * 64;
            const int kblk = k0 >> 7, cb = k0 & 64;
            stage_tile(Pbat + (triq + kblk) * BLKE + cb, 128, As, tid);
            stage_tile(Bbase + k0, NSEQ, Bs, tid);
            __syncthreads();
            mma_tiles(As, Bs, acc, wm, wn, lane);
            __syncthreads();
        }

        const int o_base = ob * 128 + wn * 64;
#pragma unroll
        for (int mt = 0; mt < 2; ++mt)
#pragma unroll
            for (int nt = 0; nt < 2; ++nt)
#pragma unroll
                for (int reg = 0; reg < 16; ++reg) {
                    const int rl = wm * 64 + mt * 32 + crow(reg, hi);
                    const int q = qb * 128 + rl;
                    Out[((size_t)(bb * NSEQ + q)) * DDIM + (o_base + nt * 32 + r32)] =
                        acc[mt][nt][reg] * Linv[rl];
                }
        // Linv rewrite for next item is fenced by the top-of-loop __syncthreads
    }
}

extern "C" void kernel_launch(void* const* d_in, const int* in_sizes, int n_in,
                              void* d_out, int out_size, void* d_ws, size_t ws_size,
                              hipStream_t stream)
{
    const float* X  = (const float*)d_in[0];
    const float* Wq = (const float*)d_in[1];
    const float* Wk = (const float*)d_in[2];
    const float* Wv = (const float*)d_in[3];
    float* Out = (float*)d_out;

    const size_t E = (size_t)NB * NSEQ * DDIM;  // 12,582,912
    char* ws = (char*)d_ws;
    unsigned short* Qb  = (unsigned short*)ws;          // E bf16
    unsigned short* Kb  = Qb + E;
    unsigned short* Vtb = Kb + E;
    unsigned short* Sbuf = Vtb + E;                     // 34,603,008 bf16 (overlay region)
    unsigned short* Xb  = Sbuf;                         // dead before Sbuf is written
    unsigned short* Wb  = Xb + E;                       // 3*589824 bf16 (also dead)
    float* L = (float*)(ws + 3 * E * 2 + (size_t)NB * NTRI * BLKE * 2);  // 16384 f32
    unsigned int* counter = (unsigned int*)(L + (size_t)NB * NSEQ);
    // ws required: 75,497,472 + 69,206,016 + 65,536 + 4 ≈ 144.77 MB

    convert_kernel<<<7024, 256, 0, stream>>>(X, Wq, Wk, Wv, Xb, Wb, L, counter);
    qkv_gemm<<<dim3(64, 3, 3), 512, 0, stream>>>(Xb, Wb, Qb, Kb, Vtb);
    gemm_s<<<dim3(136, NB), 512, 0, stream>>>(Qb, Kb, Sbuf, L);
    gemm_pv<<<512, 256, 0, stream>>>(Sbuf, Vtb, L, Out, counter);
}

// Round 4
// 369.441 us; speedup vs baseline: 1.1237x; 1.1237x over previous
//
#include <hip/hip_runtime.h>
#include <hip/hip_bf16.h>
#include <stdint.h>

#define NSEQ 4096
#define DDIM 768
#define NB   4
#define NTRI 528          // 32*33/2 lower-tri 128-blocks per batch
#define BLKE 16384        // 128*128

typedef short short8 __attribute__((ext_vector_type(8)));
typedef float f32x16 __attribute__((ext_vector_type(16)));

__device__ __forceinline__ unsigned short f2bf(float f) {
    unsigned int u = __float_as_uint(f);
    u += 0x7fffu + ((u >> 16) & 1u);
    return (unsigned short)(u >> 16);
}
__device__ __forceinline__ short8 cvt8(const float* __restrict__ p) {
    float4 x = *(const float4*)p;
    float4 y = *(const float4*)(p + 4);
    union { short8 s; __hip_bfloat162 h[4]; } u;
    u.h[0] = __float22bfloat162_rn(make_float2(x.x, x.y));
    u.h[1] = __float22bfloat162_rn(make_float2(x.z, x.w));
    u.h[2] = __float22bfloat162_rn(make_float2(y.x, y.y));
    u.h[3] = __float22bfloat162_rn(make_float2(y.z, y.w));
    return u.s;
}

// async global->LDS, 16B per lane (global_load_lds_dwordx4)
typedef const __attribute__((address_space(1))) unsigned int ga_u32;
typedef __attribute__((address_space(3))) unsigned int ls_u32;
__device__ __forceinline__ void gload_lds16(const void* g, void* l) {
    __builtin_amdgcn_global_load_lds((ga_u32*)(uintptr_t)g, (ls_u32*)(uintptr_t)l, 16, 0, 0);
}

// ---------------------------------------------------------------------------
// XOR-swizzled LDS tile (verified 0-conflict): stored 16B chunk p of row r
// holds global chunk p ^ (r&7) ^ ((r>>3)&3). Swizzle applied on the GLOBAL
// source column so the LDS dest stays wave-uniform base + lane*16.
// ---------------------------------------------------------------------------
__device__ __forceinline__ void stage_tile(const unsigned short* gbase, int stride,
                                           unsigned short* lds, int tid) {
    const int lane = tid & 63, wv = tid >> 6;
    const int r8  = lane >> 3;
    const int cl  = (lane & 7) * 8;          // LDS dest col group (lane*16B)
#pragma unroll
    for (int t = 0; t < 4; ++t) {
        const int row = wv * 32 + t * 8 + r8;
        const int csw = (((lane & 7) ^ r8 ^ t) & 7) * 8;   // swizzled global col
        gload_lds16(gbase + (size_t)row * stride + csw, lds + row * 64 + cl);
    }
}

// ---------------------------------------------------------------------------
// One BK=64 compute step with 32x32x16 MFMA: 4 k16-chunks x (4 ds_read_b128 +
// 4 MFMA). Wave tile 64x64 = 2x2 of 32x32.
// ---------------------------------------------------------------------------
__device__ __forceinline__ void mma_tiles(const unsigned short* As, const unsigned short* Bs,
                                          f32x16 acc[2][2], int wm, int wn, int lane) {
    const int r32 = lane & 31;
    const int hi  = lane >> 5;
    const int sw  = (lane & 7) ^ ((lane >> 3) & 3);
#pragma unroll
    for (int c = 0; c < 4; ++c) {
        const int chunk = (((c * 2 + hi) ^ sw) & 7) * 8;
        short8 af[2], bg[2];
#pragma unroll
        for (int mt = 0; mt < 2; ++mt)
            af[mt] = *(const short8*)(As + (wm * 64 + mt * 32 + r32) * 64 + chunk);
#pragma unroll
        for (int nt = 0; nt < 2; ++nt)
            bg[nt] = *(const short8*)(Bs + (wn * 64 + nt * 32 + r32) * 64 + chunk);
#pragma unroll
        for (int mt = 0; mt < 2; ++mt)
#pragma unroll
            for (int nt = 0; nt < 2; ++nt)
                acc[mt][nt] = __builtin_amdgcn_mfma_f32_32x32x16_bf16(af[mt], bg[nt], acc[mt][nt], 0, 0, 0);
    }
}

// C/D layout (m74/m101-verified): col = lane&31, row = (reg&3)+8*(reg>>2)+4*(lane>>5)
__device__ __forceinline__ int crow(int reg, int hi) {
    return (reg & 3) + 8 * (reg >> 2) + 4 * hi;
}

// ---------------------------------------------------------------------------
// fp32 -> bf16 convert: X (6144 blocks), Wq/Wk/Wv (288 blocks each).
// Extra 16 blocks zero the row-sum accumulator L; block 0 zeroes the counter.
// ---------------------------------------------------------------------------
__global__ __launch_bounds__(256)
void convert_kernel(const float* __restrict__ X, const float* __restrict__ Wq,
                    const float* __restrict__ Wk, const float* __restrict__ Wv,
                    unsigned short* __restrict__ Xb, unsigned short* __restrict__ Wb,
                    float* __restrict__ L, unsigned int* __restrict__ counter)
{
    const int bid = blockIdx.x;
    if (bid == 0 && threadIdx.x == 0) *counter = 0u;
    if (bid >= 7008) {                      // zero L: 16 blocks x 1024 floats
        const int idx = (bid - 7008) * 1024 + threadIdx.x * 4;
        *(float4*)(L + idx) = make_float4(0.f, 0.f, 0.f, 0.f);
        return;
    }
    const float* src; unsigned short* dst; size_t off;
    if (bid < 6144) { src = X; dst = Xb; off = (size_t)bid * 2048; }
    else {
        const int wbid = bid - 6144;
        const int wi = wbid / 288;
        src = (wi == 0) ? Wq : ((wi == 1) ? Wk : Wv);
        dst = Wb + (size_t)wi * (DDIM * DDIM);
        off = (size_t)(wbid - wi * 288) * 2048;
    }
    const size_t i = off + (size_t)threadIdx.x * 8;
    *(short8*)(dst + i) = cvt8(src + i);
}

// ---------------------------------------------------------------------------
// QKV: C = Xb * Wb^T per weight. 128x128 tile, BK=64, 256 thr. grid (128,6,3).
// T1: XCD-aware swizzle of blockIdx.x (128 = 8 XCD x 16 chunk, bijective) so
// each XCD works a contiguous 16-block M-range (A-panel 3MB ~ fits 4MB L2).
// ---------------------------------------------------------------------------
__global__ __launch_bounds__(256)
void qkv_gemm(const unsigned short* __restrict__ Xb, const unsigned short* __restrict__ Wb,
              unsigned short* __restrict__ Qb, unsigned short* __restrict__ Kb,
              unsigned short* __restrict__ Vtb)
{
    const int tid = threadIdx.x, lane = tid & 63, wv = tid >> 6;
    const int r32 = lane & 31, hi = lane >> 5, wm = wv >> 1, wn = wv & 1;
    const int bx = (blockIdx.x & 7) * 16 + (blockIdx.x >> 3);   // XCD swizzle
    const int m0 = bx * 128, n0 = blockIdx.y * 128, widx = blockIdx.z;
    const unsigned short* A = Xb + (size_t)m0 * DDIM;
    const unsigned short* B = Wb + (size_t)widx * (DDIM * DDIM) + (size_t)n0 * DDIM;

    __shared__ __align__(16) unsigned short As[128 * 64];
    __shared__ __align__(16) unsigned short Bs[128 * 64];

    f32x16 acc[2][2] = {};

    for (int kt = 0; kt < 12; ++kt) {
        stage_tile(A + kt * 64, DDIM, As, tid);
        stage_tile(B + kt * 64, DDIM, Bs, tid);
        __syncthreads();
        mma_tiles(As, Bs, acc, wm, wn, lane);
        __syncthreads();
    }

    const int m_base = m0 + wm * 64, o_base = n0 + wn * 64;
    if (widx < 2) {
        unsigned short* dst = (widx == 0) ? Qb : Kb;
#pragma unroll
        for (int mt = 0; mt < 2; ++mt)
#pragma unroll
            for (int nt = 0; nt < 2; ++nt)
#pragma unroll
                for (int reg = 0; reg < 16; ++reg)
                    dst[(size_t)(m_base + mt * 32 + crow(reg, hi)) * DDIM +
                        (o_base + nt * 32 + r32)] = f2bf(acc[mt][nt][reg]);
    } else {
        // Vt[b][o][n]: regs b4*4+0..3 are rows n, n+1, n+2, n+3 -> ushort4 pack
        const int bb = m0 >> 12;
        const int n_seq0 = (m0 & (NSEQ - 1)) + wm * 64;
#pragma unroll
        for (int mt = 0; mt < 2; ++mt)
#pragma unroll
            for (int nt = 0; nt < 2; ++nt) {
                const int o = o_base + nt * 32 + r32;
#pragma unroll
                for (int b4 = 0; b4 < 4; ++b4) {
                    ushort4 pk;
                    pk.x = f2bf(acc[mt][nt][b4 * 4 + 0]);
                    pk.y = f2bf(acc[mt][nt][b4 * 4 + 1]);
                    pk.z = f2bf(acc[mt][nt][b4 * 4 + 2]);
                    pk.w = f2bf(acc[mt][nt][b4 * 4 + 3]);
                    const int n = n_seq0 + mt * 32 + b4 * 8 + hi * 4;
                    *(ushort4*)(Vtb + ((size_t)(bb * DDIM + o)) * NSEQ + n) = pk;
                }
            }
    }
}

// ---------------------------------------------------------------------------
// S-pass, softmax fused in epilogue: P' = bf16(exp2(s*c2)) written directly
// (no max subtraction — s*c2 in [-3, +14], exp2 safe), per-row sums
// shuffle-reduced + atomicAdd into L[b][q]. Lower-tri 128-blocks only; diag
// masked to 0. grid (528, 4). T1: XCD swizzle of tri-index (528 = 8 x 66,
// bijective) keeps runs of same-Q-panel tri blocks on one XCD's L2.
// ---------------------------------------------------------------------------
__global__ __launch_bounds__(256)
void gemm_s(const unsigned short* __restrict__ Qb, const unsigned short* __restrict__ Kb,
            unsigned short* __restrict__ Sbuf, float* __restrict__ L)
{
    const float c2 = 0.05205877475f;  // log2(e)/sqrt(768)
    const int tid = threadIdx.x, lane = tid & 63, wv = tid >> 6;
    const int r32 = lane & 31, hi = lane >> 5, wm = wv >> 1, wn = wv & 1;
    const int idx = (blockIdx.x & 7) * 66 + (blockIdx.x >> 3);  // XCD swizzle
    const int bb = blockIdx.y;
    int qb = (int)((sqrtf(8.f * idx + 1.f) - 1.f) * 0.5f);
    while ((qb + 1) * (qb + 2) / 2 <= idx) ++qb;
    while (qb * (qb + 1) / 2 > idx) --qb;
    const int kb = idx - qb * (qb + 1) / 2;

    const unsigned short* A = Qb + ((size_t)bb * NSEQ + qb * 128) * DDIM;
    const unsigned short* B = Kb + ((size_t)bb * NSEQ + kb * 128) * DDIM;

    __shared__ __align__(16) unsigned short As[128 * 64];
    __shared__ __align__(16) unsigned short Bs[128 * 64];

    f32x16 acc[2][2] = {};

    for (int kt = 0; kt < 12; ++kt) {
        stage_tile(A + kt * 64, DDIM, As, tid);
        stage_tile(B + kt * 64, DDIM, Bs, tid);
        __syncthreads();
        mma_tiles(As, Bs, acc, wm, wn, lane);
        __syncthreads();
    }

    unsigned short* Sblk = Sbuf + ((size_t)(bb * NTRI + idx)) * BLKE;
    float* Lrow = L + (size_t)bb * NSEQ + qb * 128;
    const bool diag = (qb == kb);
#pragma unroll
    for (int mt = 0; mt < 2; ++mt)
#pragma unroll
        for (int rp = 0; rp < 8; ++rp) {            // reg pair: rows row0, row0+1
            const int reg0 = rp * 2, reg1 = rp * 2 + 1;
            const int row0 = wm * 64 + mt * 32 + crow(reg0, hi);
            const int row1 = row0 + 1;
            float vs0 = 0.f, vs1 = 0.f;
#pragma unroll
            for (int nt = 0; nt < 2; ++nt) {
                const int col = wn * 64 + nt * 32 + r32;
                float e0 = (diag && col > row0) ? 0.f : exp2f(acc[mt][nt][reg0] * c2);
                float e1 = (diag && col > row1) ? 0.f : exp2f(acc[mt][nt][reg1] * c2);
                union { __hip_bfloat162 h; ushort2 u; } cv;
                cv.h = __float22bfloat162_rn(make_float2(e0, e1));
                Sblk[row0 * 128 + col] = cv.u.x;
                Sblk[row1 * 128 + col] = cv.u.y;
                vs0 += e0;
                vs1 += e1;
            }
#pragma unroll
            for (int s = 1; s < 32; s <<= 1) {
                vs0 += __shfl_xor(vs0, s);
                vs1 += __shfl_xor(vs1, s);
            }
            if (r32 == 0) {
                atomicAdd(&Lrow[row0], vs0);
                atomicAdd(&Lrow[row1], vs1);
            }
        }
}

// ---------------------------------------------------------------------------
// O = P' V * (1/L[q]). Persistent queue, items (qb desc, b, ob). grid 512.
// ---------------------------------------------------------------------------
__global__ __launch_bounds__(256)
void gemm_pv(const unsigned short* __restrict__ P, const unsigned short* __restrict__ Vt,
             const float* __restrict__ L, float* __restrict__ Out,
             unsigned int* __restrict__ counter)
{
    const int tid = threadIdx.x, lane = tid & 63, wv = tid >> 6;
    const int r32 = lane & 31, hi = lane >> 5, wm = wv >> 1, wn = wv & 1;

    __shared__ __align__(16) unsigned short As[128 * 64];
    __shared__ __align__(16) unsigned short Bs[128 * 64];
    __shared__ float Linv[128];
    __shared__ unsigned int item_s;

    for (;;) {
        if (tid == 0) item_s = atomicAdd(counter, 1u);
        __syncthreads();
        const unsigned int item = item_s;
        if (item >= 768u) return;

        const int t = (int)(item / 24u);
        const int qb = 31 - t;
        const int rem = (int)(item - (unsigned)t * 24u);
        const int bb = rem / 6, ob = rem % 6;
        const size_t triq = (size_t)qb * (qb + 1) / 2;
        const unsigned short* Pbat = P + (size_t)bb * NTRI * BLKE;
        const unsigned short* Bbase = Vt + ((size_t)(bb * DDIM + ob * 128)) * NSEQ;
        const int niter = (qb + 1) * 2;

        if (tid < 128) Linv[tid] = 1.0f / L[(size_t)bb * NSEQ + qb * 128 + tid];

        f32x16 acc[2][2] = {};

        for (int it = 0; it < niter; ++it) {
            const int k0 = it * 64;
            const int kblk = k0 >> 7, cb = k0 & 64;
            stage_tile(Pbat + (triq + kblk) * BLKE + cb, 128, As, tid);
            stage_tile(Bbase + k0, NSEQ, Bs, tid);
            __syncthreads();
            mma_tiles(As, Bs, acc, wm, wn, lane);
            __syncthreads();
        }

        const int o_base = ob * 128 + wn * 64;
#pragma unroll
        for (int mt = 0; mt < 2; ++mt)
#pragma unroll
            for (int nt = 0; nt < 2; ++nt)
#pragma unroll
                for (int reg = 0; reg < 16; ++reg) {
                    const int rl = wm * 64 + mt * 32 + crow(reg, hi);
                    const int q = qb * 128 + rl;
                    Out[((size_t)(bb * NSEQ + q)) * DDIM + (o_base + nt * 32 + r32)] =
                        acc[mt][nt][reg] * Linv[rl];
                }
        // Linv rewrite for next item is fenced by the top-of-loop __syncthreads
    }
}

extern "C" void kernel_launch(void* const* d_in, const int* in_sizes, int n_in,
                              void* d_out, int out_size, void* d_ws, size_t ws_size,
                              hipStream_t stream)
{
    const float* X  = (const float*)d_in[0];
    const float* Wq = (const float*)d_in[1];
    const float* Wk = (const float*)d_in[2];
    const float* Wv = (const float*)d_in[3];
    float* Out = (float*)d_out;

    const size_t E = (size_t)NB * NSEQ * DDIM;  // 12,582,912
    char* ws = (char*)d_ws;
    unsigned short* Qb  = (unsigned short*)ws;          // E bf16
    unsigned short* Kb  = Qb + E;
    unsigned short* Vtb = Kb + E;
    unsigned short* Sbuf = Vtb + E;                     // 34,603,008 bf16 (overlay region)
    unsigned short* Xb  = Sbuf;                         // dead before Sbuf is written
    unsigned short* Wb  = Xb + E;                       // 3*589824 bf16 (also dead)
    float* L = (float*)(ws + 3 * E * 2 + (size_t)NB * NTRI * BLKE * 2);  // 16384 f32
    unsigned int* counter = (unsigned int*)(L + (size_t)NB * NSEQ);
    // ws required: 75,497,472 + 69,206,016 + 65,536 + 4 ≈ 144.77 MB

    convert_kernel<<<7024, 256, 0, stream>>>(X, Wq, Wk, Wv, Xb, Wb, L, counter);
    qkv_gemm<<<dim3(128, 6, 3), 256, 0, stream>>>(Xb, Wb, Qb, Kb, Vtb);
    gemm_s<<<dim3(528, NB), 256, 0, stream>>>(Qb, Kb, Sbuf, L);
    gemm_pv<<<512, 256, 0, stream>>>(Sbuf, Vtb, L, Out, counter);
}

// Round 6
// 362.155 us; speedup vs baseline: 1.1463x; 1.0201x over previous
//
#include <hip/hip_runtime.h>
#include <hip/hip_bf16.h>
#include <stdint.h>

#define NSEQ 4096
#define DDIM 768
#define NB   4
#define NTRI 528          // 32*33/2 lower-tri 128-blocks per batch
#define BLKE 16384        // 128*128

typedef short short8 __attribute__((ext_vector_type(8)));
typedef float f32x16 __attribute__((ext_vector_type(16)));

__device__ __forceinline__ unsigned short f2bf(float f) {
    unsigned int u = __float_as_uint(f);
    u += 0x7fffu + ((u >> 16) & 1u);
    return (unsigned short)(u >> 16);
}
__device__ __forceinline__ short8 cvt8(const float* __restrict__ p) {
    float4 x = *(const float4*)p;
    float4 y = *(const float4*)(p + 4);
    union { short8 s; __hip_bfloat162 h[4]; } u;
    u.h[0] = __float22bfloat162_rn(make_float2(x.x, x.y));
    u.h[1] = __float22bfloat162_rn(make_float2(x.z, x.w));
    u.h[2] = __float22bfloat162_rn(make_float2(y.x, y.y));
    u.h[3] = __float22bfloat162_rn(make_float2(y.z, y.w));
    return u.s;
}

// async global->LDS, 16B per lane (global_load_lds_dwordx4)
typedef const __attribute__((address_space(1))) unsigned int ga_u32;
typedef __attribute__((address_space(3))) unsigned int ls_u32;
__device__ __forceinline__ void gload_lds16(const void* g, void* l) {
    __builtin_amdgcn_global_load_lds((ga_u32*)(uintptr_t)g, (ls_u32*)(uintptr_t)l, 16, 0, 0);
}

// ---------------------------------------------------------------------------
// XOR-swizzled LDS tile (verified 0-conflict): stored 16B chunk p of row r
// holds global chunk p ^ (r&7) ^ ((r>>3)&3). Swizzle applied on the GLOBAL
// source column so the LDS dest stays wave-uniform base + lane*16.
// ---------------------------------------------------------------------------
__device__ __forceinline__ void stage_tile(const unsigned short* gbase, int stride,
                                           unsigned short* lds, int tid) {
    const int lane = tid & 63, wv = tid >> 6;
    const int r8  = lane >> 3;
    const int cl  = (lane & 7) * 8;          // LDS dest col group (lane*16B)
#pragma unroll
    for (int t = 0; t < 4; ++t) {
        const int row = wv * 32 + t * 8 + r8;
        const int csw = (((lane & 7) ^ r8 ^ t) & 7) * 8;   // swizzled global col
        gload_lds16(gbase + (size_t)row * stride + csw, lds + row * 64 + cl);
    }
}

// ---------------------------------------------------------------------------
// One BK=64 compute step with 32x32x16 MFMA: 4 k16-chunks x (4 ds_read_b128 +
// 4 MFMA). Wave tile 64x64 = 2x2 of 32x32.
// ---------------------------------------------------------------------------
__device__ __forceinline__ void mma_tiles(const unsigned short* As, const unsigned short* Bs,
                                          f32x16 acc[2][2], int wm, int wn, int lane) {
    const int r32 = lane & 31;
    const int hi  = lane >> 5;
    const int sw  = (lane & 7) ^ ((lane >> 3) & 3);
#pragma unroll
    for (int c = 0; c < 4; ++c) {
        const int chunk = (((c * 2 + hi) ^ sw) & 7) * 8;
        short8 af[2], bg[2];
#pragma unroll
        for (int mt = 0; mt < 2; ++mt)
            af[mt] = *(const short8*)(As + (wm * 64 + mt * 32 + r32) * 64 + chunk);
#pragma unroll
        for (int nt = 0; nt < 2; ++nt)
            bg[nt] = *(const short8*)(Bs + (wn * 64 + nt * 32 + r32) * 64 + chunk);
#pragma unroll
        for (int mt = 0; mt < 2; ++mt)
#pragma unroll
            for (int nt = 0; nt < 2; ++nt)
                acc[mt][nt] = __builtin_amdgcn_mfma_f32_32x32x16_bf16(af[mt], bg[nt], acc[mt][nt], 0, 0, 0);
    }
}

// PV variant: also accumulates row-sums via ones-MFMA (B = bf16 1.0 splat).
// D[r,c] = sum_k A[r,k] for every c -> accS[mt][reg] holds the row sum of
// exactly the rows acc[mt][nt][reg] covers (same C/D layout). No shuffles.
__device__ __forceinline__ void mma_tiles_pv(const unsigned short* As, const unsigned short* Bs,
                                             f32x16 acc[2][2], f32x16 accS[2], short8 ones,
                                             int wm, int wn, int lane) {
    const int r32 = lane & 31;
    const int hi  = lane >> 5;
    const int sw  = (lane & 7) ^ ((lane >> 3) & 3);
#pragma unroll
    for (int c = 0; c < 4; ++c) {
        const int chunk = (((c * 2 + hi) ^ sw) & 7) * 8;
        short8 af[2], bg[2];
#pragma unroll
        for (int mt = 0; mt < 2; ++mt)
            af[mt] = *(const short8*)(As + (wm * 64 + mt * 32 + r32) * 64 + chunk);
#pragma unroll
        for (int nt = 0; nt < 2; ++nt)
            bg[nt] = *(const short8*)(Bs + (wn * 64 + nt * 32 + r32) * 64 + chunk);
#pragma unroll
        for (int mt = 0; mt < 2; ++mt) {
#pragma unroll
            for (int nt = 0; nt < 2; ++nt)
                acc[mt][nt] = __builtin_amdgcn_mfma_f32_32x32x16_bf16(af[mt], bg[nt], acc[mt][nt], 0, 0, 0);
            accS[mt] = __builtin_amdgcn_mfma_f32_32x32x16_bf16(af[mt], ones, accS[mt], 0, 0, 0);
        }
    }
}

// C/D layout (m74/m101-verified): col = lane&31, row = (reg&3)+8*(reg>>2)+4*(lane>>5)
__device__ __forceinline__ int crow(int reg, int hi) {
    return (reg & 3) + 8 * (reg >> 2) + 4 * hi;
}

// ---------------------------------------------------------------------------
// fp32 -> bf16 convert: X (6144 blocks), Wq/Wk/Wv (288 blocks each).
// Block 0 zeroes the PV work-queue counter.
// ---------------------------------------------------------------------------
__global__ __launch_bounds__(256)
void convert_kernel(const float* __restrict__ X, const float* __restrict__ Wq,
                    const float* __restrict__ Wk, const float* __restrict__ Wv,
                    unsigned short* __restrict__ Xb, unsigned short* __restrict__ Wb,
                    unsigned int* __restrict__ counter)
{
    const int bid = blockIdx.x;
    if (bid == 0 && threadIdx.x == 0) *counter = 0u;
    const float* src; unsigned short* dst; size_t off;
    if (bid < 6144) { src = X; dst = Xb; off = (size_t)bid * 2048; }
    else {
        const int wbid = bid - 6144;
        const int wi = wbid / 288;
        src = (wi == 0) ? Wq : ((wi == 1) ? Wk : Wv);
        dst = Wb + (size_t)wi * (DDIM * DDIM);
        off = (size_t)(wbid - wi * 288) * 2048;
    }
    const size_t i = off + (size_t)threadIdx.x * 8;
    *(short8*)(dst + i) = cvt8(src + i);
}

// ---------------------------------------------------------------------------
// QKV: C = Xb * Wb^T per weight. 128x128 tile, BK=64, 256 thr. grid (128,6,3).
// ---------------------------------------------------------------------------
__global__ __launch_bounds__(256)
void qkv_gemm(const unsigned short* __restrict__ Xb, const unsigned short* __restrict__ Wb,
              unsigned short* __restrict__ Qb, unsigned short* __restrict__ Kb,
              unsigned short* __restrict__ Vtb)
{
    const int tid = threadIdx.x, lane = tid & 63, wv = tid >> 6;
    const int r32 = lane & 31, hi = lane >> 5, wm = wv >> 1, wn = wv & 1;
    const int m0 = blockIdx.x * 128, n0 = blockIdx.y * 128, widx = blockIdx.z;
    const unsigned short* A = Xb + (size_t)m0 * DDIM;
    const unsigned short* B = Wb + (size_t)widx * (DDIM * DDIM) + (size_t)n0 * DDIM;

    __shared__ __align__(16) unsigned short As[128 * 64];
    __shared__ __align__(16) unsigned short Bs[128 * 64];

    f32x16 acc[2][2] = {};

    for (int kt = 0; kt < 12; ++kt) {
        stage_tile(A + kt * 64, DDIM, As, tid);
        stage_tile(B + kt * 64, DDIM, Bs, tid);
        __syncthreads();
        mma_tiles(As, Bs, acc, wm, wn, lane);
        __syncthreads();
    }

    const int m_base = m0 + wm * 64, o_base = n0 + wn * 64;
    if (widx < 2) {
        unsigned short* dst = (widx == 0) ? Qb : Kb;
#pragma unroll
        for (int mt = 0; mt < 2; ++mt)
#pragma unroll
            for (int nt = 0; nt < 2; ++nt)
#pragma unroll
                for (int reg = 0; reg < 16; ++reg)
                    dst[(size_t)(m_base + mt * 32 + crow(reg, hi)) * DDIM +
                        (o_base + nt * 32 + r32)] = f2bf(acc[mt][nt][reg]);
    } else {
        // Vt[b][o][n]: regs b4*4+0..3 are rows n, n+1, n+2, n+3 -> ushort4 pack
        const int bb = m0 >> 12;
        const int n_seq0 = (m0 & (NSEQ - 1)) + wm * 64;
#pragma unroll
        for (int mt = 0; mt < 2; ++mt)
#pragma unroll
            for (int nt = 0; nt < 2; ++nt) {
                const int o = o_base + nt * 32 + r32;
#pragma unroll
                for (int b4 = 0; b4 < 4; ++b4) {
                    ushort4 pk;
                    pk.x = f2bf(acc[mt][nt][b4 * 4 + 0]);
                    pk.y = f2bf(acc[mt][nt][b4 * 4 + 1]);
                    pk.z = f2bf(acc[mt][nt][b4 * 4 + 2]);
                    pk.w = f2bf(acc[mt][nt][b4 * 4 + 3]);
                    const int n = n_seq0 + mt * 32 + b4 * 8 + hi * 4;
                    *(ushort4*)(Vtb + ((size_t)(bb * DDIM + o)) * NSEQ + n) = pk;
                }
            }
    }
}

// ---------------------------------------------------------------------------
// S-pass, softmax fused in epilogue: P' = bf16(exp2(s*c2)) written directly
// (no max subtraction — s*c2 in [-3, +14], exp2 safe). Row-sum machinery
// removed entirely (normalizer computed in gemm_pv by ones-MFMA).
// Lower-tri 128-blocks only; diag masked to 0. grid (528, 4).
// ---------------------------------------------------------------------------
__global__ __launch_bounds__(256)
void gemm_s(const unsigned short* __restrict__ Qb, const unsigned short* __restrict__ Kb,
            unsigned short* __restrict__ Sbuf)
{
    const float c2 = 0.05205877475f;  // log2(e)/sqrt(768)
    const int tid = threadIdx.x, lane = tid & 63, wv = tid >> 6;
    const int r32 = lane & 31, hi = lane >> 5, wm = wv >> 1, wn = wv & 1;
    const int idx = blockIdx.x, bb = blockIdx.y;
    int qb = (int)((sqrtf(8.f * idx + 1.f) - 1.f) * 0.5f);
    while ((qb + 1) * (qb + 2) / 2 <= idx) ++qb;
    while (qb * (qb + 1) / 2 > idx) --qb;
    const int kb = idx - qb * (qb + 1) / 2;

    const unsigned short* A = Qb + ((size_t)bb * NSEQ + qb * 128) * DDIM;
    const unsigned short* B = Kb + ((size_t)bb * NSEQ + kb * 128) * DDIM;

    __shared__ __align__(16) unsigned short As[128 * 64];
    __shared__ __align__(16) unsigned short Bs[128 * 64];

    f32x16 acc[2][2] = {};

    for (int kt = 0; kt < 12; ++kt) {
        stage_tile(A + kt * 64, DDIM, As, tid);
        stage_tile(B + kt * 64, DDIM, Bs, tid);
        __syncthreads();
        mma_tiles(As, Bs, acc, wm, wn, lane);
        __syncthreads();
    }

    unsigned short* Sblk = Sbuf + ((size_t)(bb * NTRI + idx)) * BLKE;
    const bool diag = (qb == kb);
#pragma unroll
    for (int mt = 0; mt < 2; ++mt)
#pragma unroll
        for (int rp = 0; rp < 8; ++rp) {            // reg pair: rows row0, row0+1
            const int reg0 = rp * 2, reg1 = rp * 2 + 1;
            const int row0 = wm * 64 + mt * 32 + crow(reg0, hi);
            const int row1 = row0 + 1;
#pragma unroll
            for (int nt = 0; nt < 2; ++nt) {
                const int col = wn * 64 + nt * 32 + r32;
                float e0 = (diag && col > row0) ? 0.f : exp2f(acc[mt][nt][reg0] * c2);
                float e1 = (diag && col > row1) ? 0.f : exp2f(acc[mt][nt][reg1] * c2);
                union { __hip_bfloat162 h; ushort2 u; } cv;
                cv.h = __float22bfloat162_rn(make_float2(e0, e1));
                Sblk[row0 * 128 + col] = cv.u.x;
                Sblk[row1 * 128 + col] = cv.u.y;
            }
        }
}

// ---------------------------------------------------------------------------
// O = (P' V) / rowsum(P'). Row sums via ones-MFMA alongside the PV product —
// each lane holds its own rows' normalizer, no shuffles/atomics/L buffer.
// Persistent queue, items (qb desc, b, ob). grid 512.
// ---------------------------------------------------------------------------
__global__ __launch_bounds__(256)
void gemm_pv(const unsigned short* __restrict__ P, const unsigned short* __restrict__ Vt,
             float* __restrict__ Out, unsigned int* __restrict__ counter)
{
    const int tid = threadIdx.x, lane = tid & 63, wv = tid >> 6;
    const int r32 = lane & 31, hi = lane >> 5, wm = wv >> 1, wn = wv & 1;

    short8 ones;
#pragma unroll
    for (int j = 0; j < 8; ++j) ones[j] = (short)0x3F80;   // bf16 1.0

    __shared__ __align__(16) unsigned short As[128 * 64];
    __shared__ __align__(16) unsigned short Bs[128 * 64];
    __shared__ unsigned int item_s;

    for (;;) {
        if (tid == 0) item_s = atomicAdd(counter, 1u);
        __syncthreads();
        const unsigned int item = item_s;
        if (item >= 768u) return;

        const int t = (int)(item / 24u);
        const int qb = 31 - t;
        const int rem = (int)(item - (unsigned)t * 24u);
        const int bb = rem / 6, ob = rem % 6;
        const size_t triq = (size_t)qb * (qb + 1) / 2;
        const unsigned short* Pbat = P + (size_t)bb * NTRI * BLKE;
        const unsigned short* Bbase = Vt + ((size_t)(bb * DDIM + ob * 128)) * NSEQ;
        const int niter = (qb + 1) * 2;

        f32x16 acc[2][2] = {};
        f32x16 accS[2] = {};

        for (int it = 0; it < niter; ++it) {
            const int k0 = it * 64;
            const int kblk = k0 >> 7, cb = k0 & 64;
            stage_tile(Pbat + (triq + kblk) * BLKE + cb, 128, As, tid);
            stage_tile(Bbase + k0, NSEQ, Bs, tid);
            __syncthreads();
            mma_tiles_pv(As, Bs, acc, accS, ones, wm, wn, lane);
            __syncthreads();
        }

        const int o_base = ob * 128 + wn * 64;
#pragma unroll
        for (int mt = 0; mt < 2; ++mt)
#pragma unroll
            for (int reg = 0; reg < 16; ++reg) {
                const int rl = wm * 64 + mt * 32 + crow(reg, hi);
                const int q = qb * 128 + rl;
                const float rs = __builtin_amdgcn_rcpf(accS[mt][reg]);
#pragma unroll
                for (int nt = 0; nt < 2; ++nt)
                    Out[((size_t)(bb * NSEQ + q)) * DDIM + (o_base + nt * 32 + r32)] =
                        acc[mt][nt][reg] * rs;
            }
    }
}

extern "C" void kernel_launch(void* const* d_in, const int* in_sizes, int n_in,
                              void* d_out, int out_size, void* d_ws, size_t ws_size,
                              hipStream_t stream)
{
    const float* X  = (const float*)d_in[0];
    const float* Wq = (const float*)d_in[1];
    const float* Wk = (const float*)d_in[2];
    const float* Wv = (const float*)d_in[3];
    float* Out = (float*)d_out;

    const size_t E = (size_t)NB * NSEQ * DDIM;  // 12,582,912
    char* ws = (char*)d_ws;
    unsigned short* Qb  = (unsigned short*)ws;          // E bf16
    unsigned short* Kb  = Qb + E;
    unsigned short* Vtb = Kb + E;
    unsigned short* Sbuf = Vtb + E;                     // 34,603,008 bf16 (overlay region)
    unsigned short* Xb  = Sbuf;                         // dead before Sbuf is written
    unsigned short* Wb  = Xb + E;                       // 3*589824 bf16 (also dead)
    unsigned int* counter = (unsigned int*)(ws + 3 * E * 2 + (size_t)NB * NTRI * BLKE * 2);
    // ws required: 75,497,472 + 69,206,016 + 4 ≈ 144.70 MB

    convert_kernel<<<7008, 256, 0, stream>>>(X, Wq, Wk, Wv, Xb, Wb, counter);
    qkv_gemm<<<dim3(128, 6, 3), 256, 0, stream>>>(Xb, Wb, Qb, Kb, Vtb);
    gemm_s<<<dim3(528, NB), 256, 0, stream>>>(Qb, Kb, Sbuf);
    gemm_pv<<<512, 256, 0, stream>>>(Sbuf, Vtb, Out, counter);
}

// Round 7
// 350.106 us; speedup vs baseline: 1.1857x; 1.0344x over previous
//
#include <hip/hip_runtime.h>
#include <hip/hip_bf16.h>
#include <stdint.h>

#define NSEQ 4096
#define DDIM 768
#define NB   4
#define NTRI 528          // 32*33/2 lower-tri 128-blocks per batch
#define BLKE 16384        // 128*128

typedef short short8 __attribute__((ext_vector_type(8)));
typedef float f32x16 __attribute__((ext_vector_type(16)));

__device__ __forceinline__ unsigned short f2bf(float f) {
    unsigned int u = __float_as_uint(f);
    u += 0x7fffu + ((u >> 16) & 1u);
    return (unsigned short)(u >> 16);
}
__device__ __forceinline__ short8 cvt8(const float* __restrict__ p) {
    float4 x = *(const float4*)p;
    float4 y = *(const float4*)(p + 4);
    union { short8 s; __hip_bfloat162 h[4]; } u;
    u.h[0] = __float22bfloat162_rn(make_float2(x.x, x.y));
    u.h[1] = __float22bfloat162_rn(make_float2(x.z, x.w));
    u.h[2] = __float22bfloat162_rn(make_float2(y.x, y.y));
    u.h[3] = __float22bfloat162_rn(make_float2(y.z, y.w));
    return u.s;
}

// async global->LDS, 16B per lane (global_load_lds_dwordx4)
typedef const __attribute__((address_space(1))) unsigned int ga_u32;
typedef __attribute__((address_space(3))) unsigned int ls_u32;
__device__ __forceinline__ void gload_lds16(const void* g, void* l) {
    __builtin_amdgcn_global_load_lds((ga_u32*)(uintptr_t)g, (ls_u32*)(uintptr_t)l, 16, 0, 0);
}

// ---------------------------------------------------------------------------
// XOR-swizzled LDS tile (verified 0-conflict): stored 16B chunk p of row r
// holds global chunk p ^ (r&7) ^ ((r>>3)&3). Swizzle applied on the GLOBAL
// source column so the LDS dest stays wave-uniform base + lane*16.
// ---------------------------------------------------------------------------
__device__ __forceinline__ void stage_tile(const unsigned short* gbase, int stride,
                                           unsigned short* lds, int tid) {
    const int lane = tid & 63, wv = tid >> 6;
    const int r8  = lane >> 3;
    const int cl  = (lane & 7) * 8;          // LDS dest col group (lane*16B)
#pragma unroll
    for (int t = 0; t < 4; ++t) {
        const int row = wv * 32 + t * 8 + r8;
        const int csw = (((lane & 7) ^ r8 ^ t) & 7) * 8;   // swizzled global col
        gload_lds16(gbase + (size_t)row * stride + csw, lds + row * 64 + cl);
    }
}

// ---------------------------------------------------------------------------
// One BK=64 compute step with 32x32x16 MFMA: 4 k16-chunks x (4 ds_read_b128 +
// 4 MFMA). Wave tile 64x64 = 2x2 of 32x32.
// ---------------------------------------------------------------------------
__device__ __forceinline__ void mma_tiles(const unsigned short* As, const unsigned short* Bs,
                                          f32x16 acc[2][2], int wm, int wn, int lane) {
    const int r32 = lane & 31;
    const int hi  = lane >> 5;
    const int sw  = (lane & 7) ^ ((lane >> 3) & 3);
#pragma unroll
    for (int c = 0; c < 4; ++c) {
        const int chunk = (((c * 2 + hi) ^ sw) & 7) * 8;
        short8 af[2], bg[2];
#pragma unroll
        for (int mt = 0; mt < 2; ++mt)
            af[mt] = *(const short8*)(As + (wm * 64 + mt * 32 + r32) * 64 + chunk);
#pragma unroll
        for (int nt = 0; nt < 2; ++nt)
            bg[nt] = *(const short8*)(Bs + (wn * 64 + nt * 32 + r32) * 64 + chunk);
#pragma unroll
        for (int mt = 0; mt < 2; ++mt)
#pragma unroll
            for (int nt = 0; nt < 2; ++nt)
                acc[mt][nt] = __builtin_amdgcn_mfma_f32_32x32x16_bf16(af[mt], bg[nt], acc[mt][nt], 0, 0, 0);
    }
}

// PV variant: also accumulates row-sums via ones-MFMA (B = bf16 1.0 splat).
// D[r,c] = sum_k A[r,k] for every c -> accS[mt][reg] holds the row sum of
// exactly the rows acc[mt][nt][reg] covers (same C/D layout). No shuffles.
__device__ __forceinline__ void mma_tiles_pv(const unsigned short* As, const unsigned short* Bs,
                                             f32x16 acc[2][2], f32x16 accS[2], short8 ones,
                                             int wm, int wn, int lane) {
    const int r32 = lane & 31;
    const int hi  = lane >> 5;
    const int sw  = (lane & 7) ^ ((lane >> 3) & 3);
#pragma unroll
    for (int c = 0; c < 4; ++c) {
        const int chunk = (((c * 2 + hi) ^ sw) & 7) * 8;
        short8 af[2], bg[2];
#pragma unroll
        for (int mt = 0; mt < 2; ++mt)
            af[mt] = *(const short8*)(As + (wm * 64 + mt * 32 + r32) * 64 + chunk);
#pragma unroll
        for (int nt = 0; nt < 2; ++nt)
            bg[nt] = *(const short8*)(Bs + (wn * 64 + nt * 32 + r32) * 64 + chunk);
#pragma unroll
        for (int mt = 0; mt < 2; ++mt) {
#pragma unroll
            for (int nt = 0; nt < 2; ++nt)
                acc[mt][nt] = __builtin_amdgcn_mfma_f32_32x32x16_bf16(af[mt], bg[nt], acc[mt][nt], 0, 0, 0);
            accS[mt] = __builtin_amdgcn_mfma_f32_32x32x16_bf16(af[mt], ones, accS[mt], 0, 0, 0);
        }
    }
}

// C/D layout (m74/m101-verified): col = lane&31, row = (reg&3)+8*(reg>>2)+4*(lane>>5)
__device__ __forceinline__ int crow(int reg, int hi) {
    return (reg & 3) + 8 * (reg >> 2) + 4 * hi;
}

// ---------------------------------------------------------------------------
// fp32 -> bf16 convert: X (6144 blocks), Wq/Wk/Wv (288 blocks each).
// Block 0 zeroes the PV work-queue counter.
// ---------------------------------------------------------------------------
__global__ __launch_bounds__(256)
void convert_kernel(const float* __restrict__ X, const float* __restrict__ Wq,
                    const float* __restrict__ Wk, const float* __restrict__ Wv,
                    unsigned short* __restrict__ Xb, unsigned short* __restrict__ Wb,
                    unsigned int* __restrict__ counter)
{
    const int bid = blockIdx.x;
    if (bid == 0 && threadIdx.x == 0) *counter = 0u;
    const float* src; unsigned short* dst; size_t off;
    if (bid < 6144) { src = X; dst = Xb; off = (size_t)bid * 2048; }
    else {
        const int wbid = bid - 6144;
        const int wi = wbid / 288;
        src = (wi == 0) ? Wq : ((wi == 1) ? Wk : Wv);
        dst = Wb + (size_t)wi * (DDIM * DDIM);
        off = (size_t)(wbid - wi * 288) * 2048;
    }
    const size_t i = off + (size_t)threadIdx.x * 8;
    *(short8*)(dst + i) = cvt8(src + i);
}

// ---------------------------------------------------------------------------
// QKV: C = Xb * Wb^T per weight. 128x128 tile, BK=64, 256 thr. grid (128,6,3).
// ---------------------------------------------------------------------------
__global__ __launch_bounds__(256)
void qkv_gemm(const unsigned short* __restrict__ Xb, const unsigned short* __restrict__ Wb,
              unsigned short* __restrict__ Qb, unsigned short* __restrict__ Kb,
              unsigned short* __restrict__ Vtb)
{
    const int tid = threadIdx.x, lane = tid & 63, wv = tid >> 6;
    const int r32 = lane & 31, hi = lane >> 5, wm = wv >> 1, wn = wv & 1;
    const int m0 = blockIdx.x * 128, n0 = blockIdx.y * 128, widx = blockIdx.z;
    const unsigned short* A = Xb + (size_t)m0 * DDIM;
    const unsigned short* B = Wb + (size_t)widx * (DDIM * DDIM) + (size_t)n0 * DDIM;

    __shared__ __align__(16) unsigned short As[128 * 64];
    __shared__ __align__(16) unsigned short Bs[128 * 64];

    f32x16 acc[2][2] = {};

    for (int kt = 0; kt < 12; ++kt) {
        stage_tile(A + kt * 64, DDIM, As, tid);
        stage_tile(B + kt * 64, DDIM, Bs, tid);
        __syncthreads();
        mma_tiles(As, Bs, acc, wm, wn, lane);
        __syncthreads();
    }

    const int m_base = m0 + wm * 64, o_base = n0 + wn * 64;
    if (widx < 2) {
        unsigned short* dst = (widx == 0) ? Qb : Kb;
#pragma unroll
        for (int mt = 0; mt < 2; ++mt)
#pragma unroll
            for (int nt = 0; nt < 2; ++nt)
#pragma unroll
                for (int reg = 0; reg < 16; ++reg)
                    dst[(size_t)(m_base + mt * 32 + crow(reg, hi)) * DDIM +
                        (o_base + nt * 32 + r32)] = f2bf(acc[mt][nt][reg]);
    } else {
        // Vt[b][o][n]: regs b4*4+0..3 are rows n, n+1, n+2, n+3 -> ushort4 pack
        const int bb = m0 >> 12;
        const int n_seq0 = (m0 & (NSEQ - 1)) + wm * 64;
#pragma unroll
        for (int mt = 0; mt < 2; ++mt)
#pragma unroll
            for (int nt = 0; nt < 2; ++nt) {
                const int o = o_base + nt * 32 + r32;
#pragma unroll
                for (int b4 = 0; b4 < 4; ++b4) {
                    ushort4 pk;
                    pk.x = f2bf(acc[mt][nt][b4 * 4 + 0]);
                    pk.y = f2bf(acc[mt][nt][b4 * 4 + 1]);
                    pk.z = f2bf(acc[mt][nt][b4 * 4 + 2]);
                    pk.w = f2bf(acc[mt][nt][b4 * 4 + 3]);
                    const int n = n_seq0 + mt * 32 + b4 * 8 + hi * 4;
                    *(ushort4*)(Vtb + ((size_t)(bb * DDIM + o)) * NSEQ + n) = pk;
                }
            }
    }
}

// ---------------------------------------------------------------------------
// S-pass, softmax fused in epilogue: P' = bf16(exp2(s*c2)) written directly
// (no max subtraction — s*c2 in [-3, +14], exp2 safe). Row-sum machinery
// removed entirely (normalizer computed in gemm_pv by ones-MFMA).
// Lower-tri 128-blocks only; diag masked to 0. grid (528, 4).
// ---------------------------------------------------------------------------
__global__ __launch_bounds__(256)
void gemm_s(const unsigned short* __restrict__ Qb, const unsigned short* __restrict__ Kb,
            unsigned short* __restrict__ Sbuf)
{
    const float c2 = 0.05205877475f;  // log2(e)/sqrt(768)
    const int tid = threadIdx.x, lane = tid & 63, wv = tid >> 6;
    const int r32 = lane & 31, hi = lane >> 5, wm = wv >> 1, wn = wv & 1;
    const int idx = blockIdx.x, bb = blockIdx.y;
    int qb = (int)((sqrtf(8.f * idx + 1.f) - 1.f) * 0.5f);
    while ((qb + 1) * (qb + 2) / 2 <= idx) ++qb;
    while (qb * (qb + 1) / 2 > idx) --qb;
    const int kb = idx - qb * (qb + 1) / 2;

    const unsigned short* A = Qb + ((size_t)bb * NSEQ + qb * 128) * DDIM;
    const unsigned short* B = Kb + ((size_t)bb * NSEQ + kb * 128) * DDIM;

    __shared__ __align__(16) unsigned short As[128 * 64];
    __shared__ __align__(16) unsigned short Bs[128 * 64];

    f32x16 acc[2][2] = {};

    for (int kt = 0; kt < 12; ++kt) {
        stage_tile(A + kt * 64, DDIM, As, tid);
        stage_tile(B + kt * 64, DDIM, Bs, tid);
        __syncthreads();
        mma_tiles(As, Bs, acc, wm, wn, lane);
        __syncthreads();
    }

    unsigned short* Sblk = Sbuf + ((size_t)(bb * NTRI + idx)) * BLKE;
    const bool diag = (qb == kb);
#pragma unroll
    for (int mt = 0; mt < 2; ++mt)
#pragma unroll
        for (int rp = 0; rp < 8; ++rp) {            // reg pair: rows row0, row0+1
            const int reg0 = rp * 2, reg1 = rp * 2 + 1;
            const int row0 = wm * 64 + mt * 32 + crow(reg0, hi);
            const int row1 = row0 + 1;
#pragma unroll
            for (int nt = 0; nt < 2; ++nt) {
                const int col = wn * 64 + nt * 32 + r32;
                float e0 = (diag && col > row0) ? 0.f : exp2f(acc[mt][nt][reg0] * c2);
                float e1 = (diag && col > row1) ? 0.f : exp2f(acc[mt][nt][reg1] * c2);
                union { __hip_bfloat162 h; ushort2 u; } cv;
                cv.h = __float22bfloat162_rn(make_float2(e0, e1));
                Sblk[row0 * 128 + col] = cv.u.x;
                Sblk[row1 * 128 + col] = cv.u.y;
            }
        }
}

// ---------------------------------------------------------------------------
// O = (P' V) / rowsum(P'). Row sums via ones-MFMA alongside the PV product —
// each lane holds its own rows' normalizer, no shuffles/atomics/L buffer.
// Persistent queue, items (qb desc, b, ob). grid 1024 (4 blocks/CU while
// work lasts; blocks drawing item>=768 exit immediately).
// ---------------------------------------------------------------------------
__global__ __launch_bounds__(256)
void gemm_pv(const unsigned short* __restrict__ P, const unsigned short* __restrict__ Vt,
             float* __restrict__ Out, unsigned int* __restrict__ counter)
{
    const int tid = threadIdx.x, lane = tid & 63, wv = tid >> 6;
    const int r32 = lane & 31, hi = lane >> 5, wm = wv >> 1, wn = wv & 1;

    short8 ones;
#pragma unroll
    for (int j = 0; j < 8; ++j) ones[j] = (short)0x3F80;   // bf16 1.0

    __shared__ __align__(16) unsigned short As[128 * 64];
    __shared__ __align__(16) unsigned short Bs[128 * 64];
    __shared__ unsigned int item_s;

    for (;;) {
        if (tid == 0) item_s = atomicAdd(counter, 1u);
        __syncthreads();
        const unsigned int item = item_s;
        if (item >= 768u) return;

        const int t = (int)(item / 24u);
        const int qb = 31 - t;
        const int rem = (int)(item - (unsigned)t * 24u);
        const int bb = rem / 6, ob = rem % 6;
        const size_t triq = (size_t)qb * (qb + 1) / 2;
        const unsigned short* Pbat = P + (size_t)bb * NTRI * BLKE;
        const unsigned short* Bbase = Vt + ((size_t)(bb * DDIM + ob * 128)) * NSEQ;
        const int niter = (qb + 1) * 2;

        f32x16 acc[2][2] = {};
        f32x16 accS[2] = {};

        for (int it = 0; it < niter; ++it) {
            const int k0 = it * 64;
            const int kblk = k0 >> 7, cb = k0 & 64;
            stage_tile(Pbat + (triq + kblk) * BLKE + cb, 128, As, tid);
            stage_tile(Bbase + k0, NSEQ, Bs, tid);
            __syncthreads();
            mma_tiles_pv(As, Bs, acc, accS, ones, wm, wn, lane);
            __syncthreads();
        }

        const int o_base = ob * 128 + wn * 64;
#pragma unroll
        for (int mt = 0; mt < 2; ++mt)
#pragma unroll
            for (int reg = 0; reg < 16; ++reg) {
                const int rl = wm * 64 + mt * 32 + crow(reg, hi);
                const int q = qb * 128 + rl;
                const float rs = __builtin_amdgcn_rcpf(accS[mt][reg]);
#pragma unroll
                for (int nt = 0; nt < 2; ++nt)
                    Out[((size_t)(bb * NSEQ + q)) * DDIM + (o_base + nt * 32 + r32)] =
                        acc[mt][nt][reg] * rs;
            }
    }
}

extern "C" void kernel_launch(void* const* d_in, const int* in_sizes, int n_in,
                              void* d_out, int out_size, void* d_ws, size_t ws_size,
                              hipStream_t stream)
{
    const float* X  = (const float*)d_in[0];
    const float* Wq = (const float*)d_in[1];
    const float* Wk = (const float*)d_in[2];
    const float* Wv = (const float*)d_in[3];
    float* Out = (float*)d_out;

    const size_t E = (size_t)NB * NSEQ * DDIM;  // 12,582,912
    char* ws = (char*)d_ws;
    unsigned short* Qb  = (unsigned short*)ws;          // E bf16
    unsigned short* Kb  = Qb + E;
    unsigned short* Vtb = Kb + E;
    unsigned short* Sbuf = Vtb + E;                     // 34,603,008 bf16 (overlay region)
    unsigned short* Xb  = Sbuf;                         // dead before Sbuf is written
    unsigned short* Wb  = Xb + E;                       // 3*589824 bf16 (also dead)
    unsigned int* counter = (unsigned int*)(ws + 3 * E * 2 + (size_t)NB * NTRI * BLKE * 2);
    // ws required: 75,497,472 + 69,206,016 + 4 ≈ 144.70 MB

    convert_kernel<<<7008, 256, 0, stream>>>(X, Wq, Wk, Wv, Xb, Wb, counter);
    qkv_gemm<<<dim3(128, 6, 3), 256, 0, stream>>>(Xb, Wb, Qb, Kb, Vtb);
    gemm_s<<<dim3(528, NB), 256, 0, stream>>>(Qb, Kb, Sbuf);
    gemm_pv<<<1024, 256, 0, stream>>>(Sbuf, Vtb, Out, counter);
}

// Round 8
// 349.290 us; speedup vs baseline: 1.1885x; 1.0023x over previous
//
#include <hip/hip_runtime.h>
#include <hip/hip_bf16.h>
#include <stdint.h>

#define NSEQ 4096
#define DDIM 768
#define NB   4
#define NTRI 528          // 32*33/2 lower-tri 128-blocks per batch
#define BLKE 16384        // 128*128

typedef short short8 __attribute__((ext_vector_type(8)));
typedef float f32x16 __attribute__((ext_vector_type(16)));

__device__ __forceinline__ unsigned short f2bf(float f) {
    unsigned int u = __float_as_uint(f);
    u += 0x7fffu + ((u >> 16) & 1u);
    return (unsigned short)(u >> 16);
}
__device__ __forceinline__ short8 cvt8(const float* __restrict__ p) {
    float4 x = *(const float4*)p;
    float4 y = *(const float4*)(p + 4);
    union { short8 s; __hip_bfloat162 h[4]; } u;
    u.h[0] = __float22bfloat162_rn(make_float2(x.x, x.y));
    u.h[1] = __float22bfloat162_rn(make_float2(x.z, x.w));
    u.h[2] = __float22bfloat162_rn(make_float2(y.x, y.y));
    u.h[3] = __float22bfloat162_rn(make_float2(y.z, y.w));
    return u.s;
}

// async global->LDS, 16B per lane (global_load_lds_dwordx4)
typedef const __attribute__((address_space(1))) unsigned int ga_u32;
typedef __attribute__((address_space(3))) unsigned int ls_u32;
__device__ __forceinline__ void gload_lds16(const void* g, void* l) {
    __builtin_amdgcn_global_load_lds((ga_u32*)(uintptr_t)g, (ls_u32*)(uintptr_t)l, 16, 0, 0);
}

// ---------------------------------------------------------------------------
// XOR-swizzled LDS tile (verified 0-conflict): stored 16B chunk p of row r
// holds global chunk p ^ (r&7) ^ ((r>>3)&3). Swizzle applied on the GLOBAL
// source column so the LDS dest stays wave-uniform base + lane*16.
// ---------------------------------------------------------------------------
__device__ __forceinline__ void stage_tile(const unsigned short* gbase, int stride,
                                           unsigned short* lds, int tid) {
    const int lane = tid & 63, wv = tid >> 6;
    const int r8  = lane >> 3;
    const int cl  = (lane & 7) * 8;          // LDS dest col group (lane*16B)
#pragma unroll
    for (int t = 0; t < 4; ++t) {
        const int row = wv * 32 + t * 8 + r8;
        const int csw = (((lane & 7) ^ r8 ^ t) & 7) * 8;   // swizzled global col
        gload_lds16(gbase + (size_t)row * stride + csw, lds + row * 64 + cl);
    }
}

// ---------------------------------------------------------------------------
// One BK=64 compute step with 32x32x16 MFMA: 4 k16-chunks x (4 ds_read_b128 +
// 4 MFMA). Wave tile 64x64 = 2x2 of 32x32.
// ---------------------------------------------------------------------------
__device__ __forceinline__ void mma_tiles(const unsigned short* As, const unsigned short* Bs,
                                          f32x16 acc[2][2], int wm, int wn, int lane) {
    const int r32 = lane & 31;
    const int hi  = lane >> 5;
    const int sw  = (lane & 7) ^ ((lane >> 3) & 3);
#pragma unroll
    for (int c = 0; c < 4; ++c) {
        const int chunk = (((c * 2 + hi) ^ sw) & 7) * 8;
        short8 af[2], bg[2];
#pragma unroll
        for (int mt = 0; mt < 2; ++mt)
            af[mt] = *(const short8*)(As + (wm * 64 + mt * 32 + r32) * 64 + chunk);
#pragma unroll
        for (int nt = 0; nt < 2; ++nt)
            bg[nt] = *(const short8*)(Bs + (wn * 64 + nt * 32 + r32) * 64 + chunk);
#pragma unroll
        for (int mt = 0; mt < 2; ++mt)
#pragma unroll
            for (int nt = 0; nt < 2; ++nt)
                acc[mt][nt] = __builtin_amdgcn_mfma_f32_32x32x16_bf16(af[mt], bg[nt], acc[mt][nt], 0, 0, 0);
    }
}

// PV variant: also accumulates row-sums via ones-MFMA (B = bf16 1.0 splat).
// D[r,c] = sum_k A[r,k] for every c -> accS[mt][reg] holds the row sum of
// exactly the rows acc[mt][nt][reg] covers (same C/D layout). No shuffles.
__device__ __forceinline__ void mma_tiles_pv(const unsigned short* As, const unsigned short* Bs,
                                             f32x16 acc[2][2], f32x16 accS[2], short8 ones,
                                             int wm, int wn, int lane) {
    const int r32 = lane & 31;
    const int hi  = lane >> 5;
    const int sw  = (lane & 7) ^ ((lane >> 3) & 3);
#pragma unroll
    for (int c = 0; c < 4; ++c) {
        const int chunk = (((c * 2 + hi) ^ sw) & 7) * 8;
        short8 af[2], bg[2];
#pragma unroll
        for (int mt = 0; mt < 2; ++mt)
            af[mt] = *(const short8*)(As + (wm * 64 + mt * 32 + r32) * 64 + chunk);
#pragma unroll
        for (int nt = 0; nt < 2; ++nt)
            bg[nt] = *(const short8*)(Bs + (wn * 64 + nt * 32 + r32) * 64 + chunk);
#pragma unroll
        for (int mt = 0; mt < 2; ++mt) {
#pragma unroll
            for (int nt = 0; nt < 2; ++nt)
                acc[mt][nt] = __builtin_amdgcn_mfma_f32_32x32x16_bf16(af[mt], bg[nt], acc[mt][nt], 0, 0, 0);
            accS[mt] = __builtin_amdgcn_mfma_f32_32x32x16_bf16(af[mt], ones, accS[mt], 0, 0, 0);
        }
    }
}

// C/D layout (m74/m101-verified): col = lane&31, row = (reg&3)+8*(reg>>2)+4*(lane>>5)
__device__ __forceinline__ int crow(int reg, int hi) {
    return (reg & 3) + 8 * (reg >> 2) + 4 * hi;
}

// ---------------------------------------------------------------------------
// fp32 -> bf16 convert: X (6144 blocks), Wq/Wk/Wv (288 blocks each).
// Block 0 zeroes the PV work-queue counter.
// ---------------------------------------------------------------------------
__global__ __launch_bounds__(256)
void convert_kernel(const float* __restrict__ X, const float* __restrict__ Wq,
                    const float* __restrict__ Wk, const float* __restrict__ Wv,
                    unsigned short* __restrict__ Xb, unsigned short* __restrict__ Wb,
                    unsigned int* __restrict__ counter)
{
    const int bid = blockIdx.x;
    if (bid == 0 && threadIdx.x == 0) *counter = 0u;
    const float* src; unsigned short* dst; size_t off;
    if (bid < 6144) { src = X; dst = Xb; off = (size_t)bid * 2048; }
    else {
        const int wbid = bid - 6144;
        const int wi = wbid / 288;
        src = (wi == 0) ? Wq : ((wi == 1) ? Wk : Wv);
        dst = Wb + (size_t)wi * (DDIM * DDIM);
        off = (size_t)(wbid - wi * 288) * 2048;
    }
    const size_t i = off + (size_t)threadIdx.x * 8;
    *(short8*)(dst + i) = cvt8(src + i);
}

// ---------------------------------------------------------------------------
// QKV: C = Xb * Wb^T per weight. 128x128 tile, BK=64, 256 thr. grid (128,6,3).
// ---------------------------------------------------------------------------
__global__ __launch_bounds__(256)
void qkv_gemm(const unsigned short* __restrict__ Xb, const unsigned short* __restrict__ Wb,
              unsigned short* __restrict__ Qb, unsigned short* __restrict__ Kb,
              unsigned short* __restrict__ Vtb)
{
    const int tid = threadIdx.x, lane = tid & 63, wv = tid >> 6;
    const int r32 = lane & 31, hi = lane >> 5, wm = wv >> 1, wn = wv & 1;
    const int m0 = blockIdx.x * 128, n0 = blockIdx.y * 128, widx = blockIdx.z;
    const unsigned short* A = Xb + (size_t)m0 * DDIM;
    const unsigned short* B = Wb + (size_t)widx * (DDIM * DDIM) + (size_t)n0 * DDIM;

    __shared__ __align__(16) unsigned short As[128 * 64];
    __shared__ __align__(16) unsigned short Bs[128 * 64];

    f32x16 acc[2][2] = {};

    for (int kt = 0; kt < 12; ++kt) {
        stage_tile(A + kt * 64, DDIM, As, tid);
        stage_tile(B + kt * 64, DDIM, Bs, tid);
        __syncthreads();
        mma_tiles(As, Bs, acc, wm, wn, lane);
        __syncthreads();
    }

    const int m_base = m0 + wm * 64, o_base = n0 + wn * 64;
    if (widx < 2) {
        unsigned short* dst = (widx == 0) ? Qb : Kb;
#pragma unroll
        for (int mt = 0; mt < 2; ++mt)
#pragma unroll
            for (int nt = 0; nt < 2; ++nt)
#pragma unroll
                for (int reg = 0; reg < 16; ++reg)
                    dst[(size_t)(m_base + mt * 32 + crow(reg, hi)) * DDIM +
                        (o_base + nt * 32 + r32)] = f2bf(acc[mt][nt][reg]);
    } else {
        // Vt[b][o][n]: regs b4*4+0..3 are rows n, n+1, n+2, n+3 -> ushort4 pack
        const int bb = m0 >> 12;
        const int n_seq0 = (m0 & (NSEQ - 1)) + wm * 64;
#pragma unroll
        for (int mt = 0; mt < 2; ++mt)
#pragma unroll
            for (int nt = 0; nt < 2; ++nt) {
                const int o = o_base + nt * 32 + r32;
#pragma unroll
                for (int b4 = 0; b4 < 4; ++b4) {
                    ushort4 pk;
                    pk.x = f2bf(acc[mt][nt][b4 * 4 + 0]);
                    pk.y = f2bf(acc[mt][nt][b4 * 4 + 1]);
                    pk.z = f2bf(acc[mt][nt][b4 * 4 + 2]);
                    pk.w = f2bf(acc[mt][nt][b4 * 4 + 3]);
                    const int n = n_seq0 + mt * 32 + b4 * 8 + hi * 4;
                    *(ushort4*)(Vtb + ((size_t)(bb * DDIM + o)) * NSEQ + n) = pk;
                }
            }
    }
}

// ---------------------------------------------------------------------------
// S-pass, softmax fused in epilogue: P' = bf16(exp2(s*c2)) written directly
// (no max subtraction — s*c2 in [-3, +14], exp2 safe). Row-sum machinery
// removed entirely (normalizer computed in gemm_pv by ones-MFMA).
// Lower-tri 128-blocks only; diag masked to 0. grid (528, 4).
// ---------------------------------------------------------------------------
__global__ __launch_bounds__(256)
void gemm_s(const unsigned short* __restrict__ Qb, const unsigned short* __restrict__ Kb,
            unsigned short* __restrict__ Sbuf)
{
    const float c2 = 0.05205877475f;  // log2(e)/sqrt(768)
    const int tid = threadIdx.x, lane = tid & 63, wv = tid >> 6;
    const int r32 = lane & 31, hi = lane >> 5, wm = wv >> 1, wn = wv & 1;
    const int idx = blockIdx.x, bb = blockIdx.y;
    int qb = (int)((sqrtf(8.f * idx + 1.f) - 1.f) * 0.5f);
    while ((qb + 1) * (qb + 2) / 2 <= idx) ++qb;
    while (qb * (qb + 1) / 2 > idx) --qb;
    const int kb = idx - qb * (qb + 1) / 2;

    const unsigned short* A = Qb + ((size_t)bb * NSEQ + qb * 128) * DDIM;
    const unsigned short* B = Kb + ((size_t)bb * NSEQ + kb * 128) * DDIM;

    __shared__ __align__(16) unsigned short As[128 * 64];
    __shared__ __align__(16) unsigned short Bs[128 * 64];

    f32x16 acc[2][2] = {};

    for (int kt = 0; kt < 12; ++kt) {
        stage_tile(A + kt * 64, DDIM, As, tid);
        stage_tile(B + kt * 64, DDIM, Bs, tid);
        __syncthreads();
        mma_tiles(As, Bs, acc, wm, wn, lane);
        __syncthreads();
    }

    unsigned short* Sblk = Sbuf + ((size_t)(bb * NTRI + idx)) * BLKE;
    const bool diag = (qb == kb);
#pragma unroll
    for (int mt = 0; mt < 2; ++mt)
#pragma unroll
        for (int rp = 0; rp < 8; ++rp) {            // reg pair: rows row0, row0+1
            const int reg0 = rp * 2, reg1 = rp * 2 + 1;
            const int row0 = wm * 64 + mt * 32 + crow(reg0, hi);
            const int row1 = row0 + 1;
#pragma unroll
            for (int nt = 0; nt < 2; ++nt) {
                const int col = wn * 64 + nt * 32 + r32;
                float e0 = (diag && col > row0) ? 0.f : exp2f(acc[mt][nt][reg0] * c2);
                float e1 = (diag && col > row1) ? 0.f : exp2f(acc[mt][nt][reg1] * c2);
                union { __hip_bfloat162 h; ushort2 u; } cv;
                cv.h = __float22bfloat162_rn(make_float2(e0, e1));
                Sblk[row0 * 128 + col] = cv.u.x;
                Sblk[row1 * 128 + col] = cv.u.y;
            }
        }
}

// ---------------------------------------------------------------------------
// O = (P' V) / rowsum(P'). Row sums via ones-MFMA alongside the PV product.
// Persistent queue, items (qb desc, b, ob). grid 1024.
// R7: double-buffered LDS + prefetch-next-tile + counted vmcnt(8) (minimum
// 2-phase, T3/T4 recipe). Raw s_barrier (NOT __syncthreads) so the prefetch
// loads stay in flight across the barrier. Race audit:
//  - prefetch targets the buffer whose readers all passed the previous
//    end-of-iter s_barrier (ds_reads retired before their MFMAs via
//    compiler lgkmcnt waits, which precede the barrier in program order);
//  - consumers read buf[cur] only after vmcnt(8/0) (FIFO retire: the 8
//    newest outstanding loads are next-tile's, so tile-cur's have landed)
//    + s_barrier (cross-wave visibility);
//  - sched_barrier(0) pins ds_reads below the barrier / stage above it.
// LDS 65 KB -> 2 blocks/CU, same as the register-imposed limit (free).
// ---------------------------------------------------------------------------
__global__ __launch_bounds__(256)
void gemm_pv(const unsigned short* __restrict__ P, const unsigned short* __restrict__ Vt,
             float* __restrict__ Out, unsigned int* __restrict__ counter)
{
    const int tid = threadIdx.x, lane = tid & 63, wv = tid >> 6;
    const int r32 = lane & 31, hi = lane >> 5, wm = wv >> 1, wn = wv & 1;

    short8 ones;
#pragma unroll
    for (int j = 0; j < 8; ++j) ones[j] = (short)0x3F80;   // bf16 1.0

    __shared__ __align__(16) unsigned short As[2][128 * 64];
    __shared__ __align__(16) unsigned short Bs[2][128 * 64];
    __shared__ unsigned int item_s;

    for (;;) {
        if (tid == 0) item_s = atomicAdd(counter, 1u);
        __syncthreads();
        const unsigned int item = item_s;
        if (item >= 768u) return;

        const int t = (int)(item / 24u);
        const int qb = 31 - t;
        const int rem = (int)(item - (unsigned)t * 24u);
        const int bb = rem / 6, ob = rem % 6;
        const size_t triq = (size_t)qb * (qb + 1) / 2;
        const unsigned short* Pbat = P + (size_t)bb * NTRI * BLKE;
        const unsigned short* Bbase = Vt + ((size_t)(bb * DDIM + ob * 128)) * NSEQ;
        const int niter = (qb + 1) * 2;

        f32x16 acc[2][2] = {};
        f32x16 accS[2] = {};

        // prologue: stage tile 0 into buf 0
        stage_tile(Pbat + triq * BLKE, 128, As[0], tid);
        stage_tile(Bbase, NSEQ, Bs[0], tid);

        int cur = 0;
        for (int it = 0; it < niter; ++it) {
            if (it + 1 < niter) {
                const int k1 = (it + 1) * 64;
                const int kb1 = k1 >> 7, cb1 = k1 & 64;
                stage_tile(Pbat + (triq + kb1) * BLKE + cb1, 128, As[cur ^ 1], tid);
                stage_tile(Bbase + k1, NSEQ, Bs[cur ^ 1], tid);
                asm volatile("s_waitcnt vmcnt(8)" ::: "memory");
            } else {
                asm volatile("s_waitcnt vmcnt(0)" ::: "memory");
            }
            __builtin_amdgcn_s_barrier();
            __builtin_amdgcn_sched_barrier(0);
            mma_tiles_pv(As[cur], Bs[cur], acc, accS, ones, wm, wn, lane);
            __builtin_amdgcn_sched_barrier(0);
            __builtin_amdgcn_s_barrier();
            cur ^= 1;
        }

        const int o_base = ob * 128 + wn * 64;
#pragma unroll
        for (int mt = 0; mt < 2; ++mt)
#pragma unroll
            for (int reg = 0; reg < 16; ++reg) {
                const int rl = wm * 64 + mt * 32 + crow(reg, hi);
                const int q = qb * 128 + rl;
                const float rs = __builtin_amdgcn_rcpf(accS[mt][reg]);
#pragma unroll
                for (int nt = 0; nt < 2; ++nt)
                    Out[((size_t)(bb * NSEQ + q)) * DDIM + (o_base + nt * 32 + r32)] =
                        acc[mt][nt][reg] * rs;
            }
    }
}

extern "C" void kernel_launch(void* const* d_in, const int* in_sizes, int n_in,
                              void* d_out, int out_size, void* d_ws, size_t ws_size,
                              hipStream_t stream)
{
    const float* X  = (const float*)d_in[0];
    const float* Wq = (const float*)d_in[1];
    const float* Wk = (const float*)d_in[2];
    const float* Wv = (const float*)d_in[3];
    float* Out = (float*)d_out;

    const size_t E = (size_t)NB * NSEQ * DDIM;  // 12,582,912
    char* ws = (char*)d_ws;
    unsigned short* Qb  = (unsigned short*)ws;          // E bf16
    unsigned short* Kb  = Qb + E;
    unsigned short* Vtb = Kb + E;
    unsigned short* Sbuf = Vtb + E;                     // 34,603,008 bf16 (overlay region)
    unsigned short* Xb  = Sbuf;                         // dead before Sbuf is written
    unsigned short* Wb  = Xb + E;                       // 3*589824 bf16 (also dead)
    unsigned int* counter = (unsigned int*)(ws + 3 * E * 2 + (size_t)NB * NTRI * BLKE * 2);
    // ws required: 75,497,472 + 69,206,016 + 4 ≈ 144.70 MB

    convert_kernel<<<7008, 256, 0, stream>>>(X, Wq, Wk, Wv, Xb, Wb, counter);
    qkv_gemm<<<dim3(128, 6, 3), 256, 0, stream>>>(Xb, Wb, Qb, Kb, Vtb);
    gemm_s<<<dim3(528, NB), 256, 0, stream>>>(Qb, Kb, Sbuf);
    gemm_pv<<<1024, 256, 0, stream>>>(Sbuf, Vtb, Out, counter);
}